// Round 5
// baseline (134.107 us; speedup 1.0000x reference)
//
#include <hip/hip_runtime.h>
#include <hip/hip_bf16.h>

#define N 4096
#define HID 256
#define NH 8
#define HD 32
#define NC 784    // 256 Q | 256 K | 256 V | 16 EG
#define CH 8      // j-chunks (ws >= 41 MB proven)
#define JSPAN (N / CH)

typedef __attribute__((ext_vector_type(8))) short short8;
typedef __attribute__((ext_vector_type(4))) short short4v;
typedef __attribute__((ext_vector_type(4))) float f32x4;
typedef __attribute__((ext_vector_type(2))) unsigned int uint2v;
typedef __attribute__((ext_vector_type(4))) unsigned int uint4v;

// Q scale = (1/sqrt(32)) * log2(e): folds softmax temp AND exp->exp2 conversion
#define QSCALE 0.25503482f

static __device__ __forceinline__ unsigned short f2bf(float f) {
    union { float f; unsigned u; } v; v.f = f;
    unsigned r = v.u + 0x7fff + ((v.u >> 16) & 1);
    return (unsigned short)(r >> 16);
}
static __device__ __forceinline__ unsigned packbf2(float a, float b) {
    __hip_bfloat162 t = __float22bfloat162_rn(make_float2(a, b));
    unsigned u; __builtin_memcpy(&u, &t, 4); return u;
}

// ---- fused prep: feat->bf16 (blocks 0..1023) | WbT/bC build + colS zero ----
__global__ void k_prep(const float* __restrict__ feat, const float* __restrict__ Wq,
                       const float* __restrict__ Wkv, const float* __restrict__ Weg,
                       const float* __restrict__ bq, const float* __restrict__ bkv,
                       const float* __restrict__ beg, unsigned short* __restrict__ featb,
                       unsigned short* __restrict__ WbT, float* __restrict__ bC,
                       float* __restrict__ colS) {
    int bx = blockIdx.x;
    if (bx < 1024) {
        int t = bx * 256 + threadIdx.x;
        float4 v = ((const float4*)feat)[t];
        short4v o;
        o[0] = (short)f2bf(v.x); o[1] = (short)f2bf(v.y);
        o[2] = (short)f2bf(v.z); o[3] = (short)f2bf(v.w);
        ((short4v*)featb)[t] = o;
    } else {
        int c = bx - 1024, k = threadIdx.x;
        float w, b;
        if (c < 256)      { w = Wq[k * 256 + c];          b = bq[c]; }
        else if (c < 768) { w = Wkv[k * 512 + (c - 256)]; b = bkv[c - 256]; }
        else              { w = Weg[k * 16 + (c - 768)];  b = beg[c - 768]; }
        WbT[c * 256 + k] = f2bf(w);
        if (k == 0) bC[c] = b;
        if (c < 128) colS[c * 256 + k] = 0.f;
    }
}

// ---- projection GEMM: [4096,256]x[256,784]; scatter into packed layouts ----
__global__ __launch_bounds__(256) void k_proj(const unsigned short* __restrict__ featb,
                                              const unsigned short* __restrict__ WbT,
                                              const float* __restrict__ bC,
                                              unsigned short* __restrict__ Qp,
                                              unsigned short* __restrict__ Kp,
                                              unsigned short* __restrict__ VpT,
                                              float* __restrict__ sigG) {
    int w = threadIdx.x >> 6, l = threadIdx.x & 63;
    int il = l & 15, g = l >> 4;
    int c0 = blockIdx.x * 16;
    int i0 = (blockIdx.y * 4 + w) * 16;
    const short8* Arow = (const short8*)(featb + (size_t)(i0 + il) * HID);
    const short8* Brow = (const short8*)(WbT + (size_t)(c0 + il) * HID);
    f32x4 acc = {0.f, 0.f, 0.f, 0.f};
#pragma unroll
    for (int k0 = 0; k0 < HID; k0 += 32) {
        short8 a = Arow[(k0 >> 3) + g];
        short8 b = Brow[(k0 >> 3) + g];
        acc = __builtin_amdgcn_mfma_f32_16x16x32_bf16(a, b, acc, 0, 0, 0);
    }
    int c = c0 + il;
    float bias = bC[c];
#pragma unroll
    for (int r = 0; r < 4; ++r) {
        int i = i0 + g * 4 + r;
        float val = acc[r] + bias;
        if (c < 256) {
            int h = c & 7, d = c >> 3;
            Qp[((size_t)h * N + i) * HD + d] = f2bf(val * QSCALE);
        } else if (c < 512) {
            int cc = c - 256, h = cc & 7, d = cc >> 3;
            Kp[((size_t)h * N + i) * HD + d] = f2bf(val);
        } else if (c < 768) {
            int cc = c - 512, h = cc & 7, d = cc >> 3;
            VpT[((size_t)h * HD + d) * N + i] = f2bf(val);
        } else {
            int cc = c - 768;
            if (cc >= 8) sigG[(size_t)(cc - 8) * N + i] = 1.f / (1.f + __expf(-val));
        }
    }
}

// ---- pass 1: colS[j,h] += sum_i 2^(S2_ij)  (Q prescaled by log2e) ----
__global__ __launch_bounds__(256) void k_pass1(const unsigned short* __restrict__ Qp,
                                               const unsigned short* __restrict__ Kp,
                                               float* __restrict__ colS) {
    int w = threadIdx.x >> 6, l = threadIdx.x & 63;
    int il = l & 15, g = l >> 4;
    int h = blockIdx.y;
    int j0 = (blockIdx.x * 4 + w) * 32;
    const unsigned short* Kh = Kp + (size_t)h * N * HD;
    short8 Kf0 = *(const short8*)(Kh + (size_t)(j0 + il) * HD + g * 8);
    short8 Kf1 = *(const short8*)(Kh + (size_t)(j0 + 16 + il) * HD + g * 8);
    const unsigned short* Qh = Qp + (size_t)h * N * HD;
    f32x4 z = {0.f, 0.f, 0.f, 0.f};
    float s0 = 0.f, s1 = 0.f;
    int ibeg = blockIdx.z * 512, iend = ibeg + 512;
    for (int i0 = ibeg; i0 < iend; i0 += 16) {
        short8 Qf = *(const short8*)(Qh + (size_t)(i0 + il) * HD + g * 8);
        f32x4 Sa = __builtin_amdgcn_mfma_f32_16x16x32_bf16(Qf, Kf0, z, 0, 0, 0);
        f32x4 Sb = __builtin_amdgcn_mfma_f32_16x16x32_bf16(Qf, Kf1, z, 0, 0, 0);
        s0 += (__builtin_amdgcn_exp2f(Sa[0]) + __builtin_amdgcn_exp2f(Sa[1]))
            + (__builtin_amdgcn_exp2f(Sa[2]) + __builtin_amdgcn_exp2f(Sa[3]));
        s1 += (__builtin_amdgcn_exp2f(Sb[0]) + __builtin_amdgcn_exp2f(Sb[1]))
            + (__builtin_amdgcn_exp2f(Sb[2]) + __builtin_amdgcn_exp2f(Sb[3]));
    }
#pragma unroll
    for (int off = 16; off <= 32; off <<= 1) {
        s0 += __shfl_xor(s0, off);
        s1 += __shfl_xor(s1, off);
    }
    if (g == 0) {
        atomicAdd(&colS[(size_t)h * N + j0 + il], s0);
        atomicAdd(&colS[(size_t)h * N + j0 + 16 + il], s1);
    }
}

// ---- lc2 = log2(sigG / colS), 32768 elements ----
__global__ void k_lc2(const float* __restrict__ sigG, const float* __restrict__ colS,
                      float* __restrict__ lc2) {
    int t = blockIdx.x * blockDim.x + threadIdx.x;
    f32x4 a = ((const f32x4*)sigG)[t];
    f32x4 b = ((const f32x4*)colS)[t];
    f32x4 o;
#pragma unroll
    for (int r = 0; r < 4; ++r) o[r] = __builtin_amdgcn_logf(a[r] / b[r]);
    ((f32x4*)lc2)[t] = o;
}

#if __has_builtin(__builtin_amdgcn_permlane16_swap) && __has_builtin(__builtin_amdgcn_permlane32_swap)
#define HAVE_PERMLANE 1
#else
#define HAVE_PERMLANE 0
#endif

#if HAVE_PERMLANE
// Assemble PV A-frag in registers from swapped-QK outputs.
// Inputs: Sa = scores for j-half0 (lane(il,g) holds j=4g+r, i=il),
//         Sb = j-half1. Output: lane(il,g) holds P[i=il][j=8g..8g+7] as short8.
static __device__ __forceinline__ short8 frag_dance(f32x4 Sa, f32x4 Sb) {
    unsigned A0 = packbf2(__builtin_amdgcn_exp2f(Sa[0]), __builtin_amdgcn_exp2f(Sa[1]));
    unsigned A1 = packbf2(__builtin_amdgcn_exp2f(Sa[2]), __builtin_amdgcn_exp2f(Sa[3]));
    unsigned B0 = packbf2(__builtin_amdgcn_exp2f(Sb[0]), __builtin_amdgcn_exp2f(Sb[1]));
    unsigned B1 = packbf2(__builtin_amdgcn_exp2f(Sb[2]), __builtin_amdgcn_exp2f(Sb[3]));
    uint2v r1 = __builtin_amdgcn_permlane32_swap(A0, B0, false, false);
    uint2v r2 = __builtin_amdgcn_permlane16_swap(r1[0], r1[1], false, false); // dw0, dw2
    uint2v r3 = __builtin_amdgcn_permlane32_swap(A1, B1, false, false);
    uint2v r4 = __builtin_amdgcn_permlane16_swap(r3[0], r3[1], false, false); // dw1, dw3
    uint4v pu;
    pu[0] = r2[0]; pu[1] = r4[0]; pu[2] = r2[1]; pu[3] = r4[1];
    return __builtin_bit_cast(short8, pu);
}
#endif

// ---- pass 2: Vpart[z][h][i][d] = sum_{j in chunk} 2^(S2+lc2[j]) * V[j,d] ----
// grid (32, NH, CH): x*4+w = i-tile of 32 rows, z = j-chunk of 512
__global__ __launch_bounds__(256) void k_pass2(const unsigned short* __restrict__ Qp,
                                               const unsigned short* __restrict__ Kp,
                                               const unsigned short* __restrict__ VpT,
                                               const float* __restrict__ lc2,
                                               float* __restrict__ Vpart) {
    int w = threadIdx.x >> 6, l = threadIdx.x & 63;
    int il = l & 15, g = l >> 4;
    int h = blockIdx.y;
    int i0 = (blockIdx.x * 4 + w) * 32;
    int jbeg = blockIdx.z * JSPAN;
    const unsigned short* Qh = Qp + (size_t)h * N * HD;
    const unsigned short* Kh = Kp + (size_t)h * N * HD + (size_t)jbeg * HD;
    const unsigned short* Vh = VpT + (size_t)h * HD * N + jbeg;
    const float* lcg = lc2 + (size_t)h * N + jbeg;
    short8 Qf0 = *(const short8*)(Qh + (size_t)(i0 + il) * HD + g * 8);
    short8 Qf1 = *(const short8*)(Qh + (size_t)(i0 + 16 + il) * HD + g * 8);
    f32x4 zz = {0.f, 0.f, 0.f, 0.f};
    f32x4 acc00 = zz, acc01 = zz, acc10 = zz, acc11 = zz;
#if HAVE_PERMLANE
    for (int jb = 0; jb < JSPAN; jb += 32) {
        short8 KfA = *(const short8*)(Kh + (size_t)(jb + il) * HD + g * 8);
        short8 KfB = *(const short8*)(Kh + (size_t)(jb + 16 + il) * HD + g * 8);
        f32x4 lcvA = *(const f32x4*)(lcg + jb + g * 4);
        f32x4 lcvB = *(const f32x4*)(lcg + jb + 16 + g * 4);
        // swapped QK: lane(il,g) gets S[j=4g+r][i=il] (+lc2 via C-operand)
        f32x4 S0A = __builtin_amdgcn_mfma_f32_16x16x32_bf16(KfA, Qf0, lcvA, 0, 0, 0);
        f32x4 S0B = __builtin_amdgcn_mfma_f32_16x16x32_bf16(KfB, Qf0, lcvB, 0, 0, 0);
        f32x4 S1A = __builtin_amdgcn_mfma_f32_16x16x32_bf16(KfA, Qf1, lcvA, 0, 0, 0);
        f32x4 S1B = __builtin_amdgcn_mfma_f32_16x16x32_bf16(KfB, Qf1, lcvB, 0, 0, 0);
        short8 Pa0 = frag_dance(S0A, S0B);   // i-half0 A-frag
        short8 Pa1 = frag_dance(S1A, S1B);   // i-half1 A-frag
        short8 Vb0 = *(const short8*)(Vh + (size_t)il * N + jb + g * 8);
        short8 Vb1 = *(const short8*)(Vh + (size_t)(16 + il) * N + jb + g * 8);
        acc00 = __builtin_amdgcn_mfma_f32_16x16x32_bf16(Pa0, Vb0, acc00, 0, 0, 0);
        acc01 = __builtin_amdgcn_mfma_f32_16x16x32_bf16(Pa0, Vb1, acc01, 0, 0, 0);
        acc10 = __builtin_amdgcn_mfma_f32_16x16x32_bf16(Pa1, Vb0, acc10, 0, 0, 0);
        acc11 = __builtin_amdgcn_mfma_f32_16x16x32_bf16(Pa1, Vb1, acc11, 0, 0, 0);
    }
#else
    // fallback: per-wave LDS P staging (round-4 path, PSTR=40)
    __shared__ __align__(16) unsigned short Pl[4][32 * 40];
    unsigned short* P = Pl[w];
    for (int jb = 0; jb < JSPAN; jb += 32) {
#pragma unroll
        for (int half = 0; half < 2; ++half) {
            int jloc = jb + half * 16;
            short8 Kf = *(const short8*)(Kh + (size_t)(jloc + il) * HD + g * 8);
            f32x4 lcv = *(const f32x4*)(lcg + jloc + g * 4);
            f32x4 S0 = __builtin_amdgcn_mfma_f32_16x16x32_bf16(Kf, Qf0, lcv, 0, 0, 0);
            f32x4 S1 = __builtin_amdgcn_mfma_f32_16x16x32_bf16(Kf, Qf1, lcv, 0, 0, 0);
            unsigned* dst0 = (unsigned*)(P + (size_t)il * 40 + half * 16 + g * 4);
            dst0[0] = packbf2(__builtin_amdgcn_exp2f(S0[0]), __builtin_amdgcn_exp2f(S0[1]));
            dst0[1] = packbf2(__builtin_amdgcn_exp2f(S0[2]), __builtin_amdgcn_exp2f(S0[3]));
            unsigned* dst1 = (unsigned*)(P + (size_t)(16 + il) * 40 + half * 16 + g * 4);
            dst1[0] = packbf2(__builtin_amdgcn_exp2f(S1[0]), __builtin_amdgcn_exp2f(S1[1]));
            dst1[1] = packbf2(__builtin_amdgcn_exp2f(S1[2]), __builtin_amdgcn_exp2f(S1[3]));
        }
        short8 Pa0 = *(const short8*)(P + (size_t)il * 40 + g * 8);
        short8 Pa1 = *(const short8*)(P + (size_t)(16 + il) * 40 + g * 8);
        short8 Vb0 = *(const short8*)(Vh + (size_t)il * N + jb + g * 8);
        short8 Vb1 = *(const short8*)(Vh + (size_t)(16 + il) * N + jb + g * 8);
        acc00 = __builtin_amdgcn_mfma_f32_16x16x32_bf16(Pa0, Vb0, acc00, 0, 0, 0);
        acc01 = __builtin_amdgcn_mfma_f32_16x16x32_bf16(Pa0, Vb1, acc01, 0, 0, 0);
        acc10 = __builtin_amdgcn_mfma_f32_16x16x32_bf16(Pa1, Vb0, acc10, 0, 0, 0);
        acc11 = __builtin_amdgcn_mfma_f32_16x16x32_bf16(Pa1, Vb1, acc11, 0, 0, 0);
    }
#endif
    float* Vout = Vpart + (size_t)(blockIdx.z * NH + h) * N * HD;
#pragma unroll
    for (int r = 0; r < 4; ++r) {
        int ia = i0 + g * 4 + r, ib = i0 + 16 + g * 4 + r;
        Vout[(size_t)ia * HD + il]      = acc00[r];   // coalesced 64B per quarter-wave
        Vout[(size_t)ia * HD + 16 + il] = acc01[r];
        Vout[(size_t)ib * HD + il]      = acc10[r];
        Vout[(size_t)ib * HD + 16 + il] = acc11[r];
    }
}

// ---- layernorm: sum CH partials (layout [ch][h][i][d]), normalize, scatter ----
__global__ __launch_bounds__(256) void k_ln(const float* __restrict__ Vpart,
                                            const float* __restrict__ gam,
                                            const float* __restrict__ bet,
                                            float* __restrict__ out) {
    int w = threadIdx.x >> 6, l = threadIdx.x & 63;
    int i = blockIdx.x * 4 + w;
    int h = l >> 3, d0 = (l & 7) << 2;   // lane owns channels c = (d0+r)*8 + h
    f32x4 x = {0.f, 0.f, 0.f, 0.f};
#pragma unroll
    for (int c = 0; c < CH; ++c) {
        f32x4 v = *(const f32x4*)(Vpart + ((size_t)(c * NH + h) * N + i) * HD + d0);
        x[0] += v[0]; x[1] += v[1]; x[2] += v[2]; x[3] += v[3];
    }
    float s1 = x[0] + x[1] + x[2] + x[3];
    float s2 = x[0] * x[0] + x[1] * x[1] + x[2] * x[2] + x[3] * x[3];
#pragma unroll
    for (int off = 1; off < 64; off <<= 1) {
        s1 += __shfl_xor(s1, off);
        s2 += __shfl_xor(s2, off);
    }
    float mu = s1 * (1.f / 256.f);
    float var = s2 * (1.f / 256.f) - mu * mu;
    float rs = rsqrtf(var + 1e-3f);
#pragma unroll
    for (int r = 0; r < 4; ++r) {
        int c = (d0 + r) * 8 + h;
        out[(size_t)i * HID + c] = (x[r] - mu) * rs * gam[c] + bet[c];
    }
}

extern "C" void kernel_launch(void* const* d_in, const int* in_sizes, int n_in,
                              void* d_out, int out_size, void* d_ws, size_t ws_size,
                              hipStream_t stream) {
    const float* feat = (const float*)d_in[0];
    const float* Wq   = (const float*)d_in[1];
    const float* bq   = (const float*)d_in[2];
    const float* Wkv  = (const float*)d_in[3];
    const float* bkv  = (const float*)d_in[4];
    const float* Weg  = (const float*)d_in[5];
    const float* beg  = (const float*)d_in[6];
    const float* ln_g = (const float*)d_in[7];
    const float* ln_b = (const float*)d_in[8];
    float* out = (float*)d_out;

    char* ws = (char*)d_ws;
    unsigned short* Qp    = (unsigned short*)(ws + 0);                     // 2 MB
    unsigned short* Kp    = (unsigned short*)(ws + (2u << 20));            // 2 MB
    unsigned short* VpT   = (unsigned short*)(ws + (4u << 20));            // 2 MB
    unsigned short* featb = (unsigned short*)(ws + (6u << 20));            // 2 MB
    unsigned short* WbT   = (unsigned short*)(ws + (8u << 20));            // 0.4 MB
    float* bC   = (float*)(ws + (8u << 20) + (512u << 10));                // 3 KB
    float* sigG = (float*)(ws + (8u << 20) + (528u << 10));                // 128 KB
    float* colS = (float*)(ws + (8u << 20) + (656u << 10));                // 128 KB
    float* lc2  = (float*)(ws + (8u << 20) + (784u << 10));                // 128 KB
    float* Vpart = (float*)(ws + (9u << 20));                              // CH*4 MB

    k_prep<<<dim3(1024 + NC), 256, 0, stream>>>(feat, Wq, Wkv, Weg, bq, bkv, beg,
                                                featb, WbT, bC, colS);
    k_proj<<<dim3(49, 64), 256, 0, stream>>>(featb, WbT, bC, Qp, Kp, VpT, sigG);
    k_pass1<<<dim3(32, NH, 8), 256, 0, stream>>>(Qp, Kp, colS);
    k_lc2<<<dim3(32), 256, 0, stream>>>(sigG, colS, lc2);
    k_pass2<<<dim3(32, NH, CH), 256, 0, stream>>>(Qp, Kp, VpT, lc2, Vpart);
    k_ln<<<dim3(1024), 256, 0, stream>>>(Vpart, ln_g, ln_b, out);
}

// Round 6
// 111.084 us; speedup vs baseline: 1.2073x; 1.2073x over previous
//
#include <hip/hip_runtime.h>
#include <hip/hip_bf16.h>

#define N 4096
#define HID 256
#define NH 8
#define HD 32
#define NC 784    // 256 Q | 256 K | 256 V | 16 EG
#define CH 8      // j-chunks (ws >= 41 MB proven)
#define JSPAN (N / CH)

typedef __attribute__((ext_vector_type(8))) short short8;
typedef __attribute__((ext_vector_type(4))) short short4v;
typedef __attribute__((ext_vector_type(4))) float f32x4;
typedef __attribute__((ext_vector_type(2))) unsigned int uint2v;
typedef __attribute__((ext_vector_type(4))) unsigned int uint4v;

// Q scale = (1/sqrt(32)) * log2(e): folds softmax temp AND exp->exp2 conversion
#define QSCALE 0.25503482f

static __device__ __forceinline__ unsigned short f2bf(float f) {
    union { float f; unsigned u; } v; v.f = f;
    unsigned r = v.u + 0x7fff + ((v.u >> 16) & 1);
    return (unsigned short)(r >> 16);
}
static __device__ __forceinline__ unsigned packbf2(float a, float b) {
    __hip_bfloat162 t = __float22bfloat162_rn(make_float2(a, b));
    unsigned u; __builtin_memcpy(&u, &t, 4); return u;
}

// ---- fused prep: feat->bf16 (blocks 0..1023) | WbT/bC build + colS zero ----
__global__ void k_prep(const float* __restrict__ feat, const float* __restrict__ Wq,
                       const float* __restrict__ Wkv, const float* __restrict__ Weg,
                       const float* __restrict__ bq, const float* __restrict__ bkv,
                       const float* __restrict__ beg, unsigned short* __restrict__ featb,
                       unsigned short* __restrict__ WbT, float* __restrict__ bC,
                       float* __restrict__ colS) {
    int bx = blockIdx.x;
    if (bx < 1024) {
        int t = bx * 256 + threadIdx.x;
        float4 v = ((const float4*)feat)[t];
        short4v o;
        o[0] = (short)f2bf(v.x); o[1] = (short)f2bf(v.y);
        o[2] = (short)f2bf(v.z); o[3] = (short)f2bf(v.w);
        ((short4v*)featb)[t] = o;
    } else {
        int c = bx - 1024, k = threadIdx.x;
        float w, b;
        if (c < 256)      { w = Wq[k * 256 + c];          b = bq[c]; }
        else if (c < 768) { w = Wkv[k * 512 + (c - 256)]; b = bkv[c - 256]; }
        else              { w = Weg[k * 16 + (c - 768)];  b = beg[c - 768]; }
        WbT[c * 256 + k] = f2bf(w);
        if (k == 0) bC[c] = b;
        if (c < 128) colS[c * 256 + k] = 0.f;
    }
}

// ---- projection GEMM: [4096,256]x[256,784]; scatter into packed layouts ----
__global__ __launch_bounds__(256) void k_proj(const unsigned short* __restrict__ featb,
                                              const unsigned short* __restrict__ WbT,
                                              const float* __restrict__ bC,
                                              unsigned short* __restrict__ Qp,
                                              unsigned short* __restrict__ Kp,
                                              unsigned short* __restrict__ VpT,
                                              float* __restrict__ sigG) {
    int w = threadIdx.x >> 6, l = threadIdx.x & 63;
    int il = l & 15, g = l >> 4;
    int c0 = blockIdx.x * 16;
    int i0 = (blockIdx.y * 4 + w) * 16;
    const short8* Arow = (const short8*)(featb + (size_t)(i0 + il) * HID);
    const short8* Brow = (const short8*)(WbT + (size_t)(c0 + il) * HID);
    f32x4 acc = {0.f, 0.f, 0.f, 0.f};
#pragma unroll
    for (int k0 = 0; k0 < HID; k0 += 32) {
        short8 a = Arow[(k0 >> 3) + g];
        short8 b = Brow[(k0 >> 3) + g];
        acc = __builtin_amdgcn_mfma_f32_16x16x32_bf16(a, b, acc, 0, 0, 0);
    }
    int c = c0 + il;
    float bias = bC[c];
#pragma unroll
    for (int r = 0; r < 4; ++r) {
        int i = i0 + g * 4 + r;
        float val = acc[r] + bias;
        if (c < 256) {
            int h = c & 7, d = c >> 3;
            Qp[((size_t)h * N + i) * HD + d] = f2bf(val * QSCALE);
        } else if (c < 512) {
            int cc = c - 256, h = cc & 7, d = cc >> 3;
            Kp[((size_t)h * N + i) * HD + d] = f2bf(val);
        } else if (c < 768) {
            int cc = c - 512, h = cc & 7, d = cc >> 3;
            VpT[((size_t)h * HD + d) * N + i] = f2bf(val);
        } else {
            int cc = c - 768;
            if (cc >= 8) sigG[(size_t)(cc - 8) * N + i] = 1.f / (1.f + __expf(-val));
        }
    }
}

// ---- pass 1: colS[j,h] += sum_i 2^(S2_ij); 32-i unroll + 1-deep Q prefetch ----
// grid (32, NH, 8): x*4+w = j-tile of 32, z = i-chunk of 512
__global__ __launch_bounds__(256) void k_pass1(const unsigned short* __restrict__ Qp,
                                               const unsigned short* __restrict__ Kp,
                                               float* __restrict__ colS) {
    int w = threadIdx.x >> 6, l = threadIdx.x & 63;
    int il = l & 15, g = l >> 4;
    int h = blockIdx.y;
    int j0 = (blockIdx.x * 4 + w) * 32;
    const unsigned short* Kh = Kp + (size_t)h * N * HD;
    short8 Kf0 = *(const short8*)(Kh + (size_t)(j0 + il) * HD + g * 8);
    short8 Kf1 = *(const short8*)(Kh + (size_t)(j0 + 16 + il) * HD + g * 8);
    const unsigned short* Qh = Qp + (size_t)h * N * HD;
    f32x4 z = {0.f, 0.f, 0.f, 0.f};
    float s0 = 0.f, s1 = 0.f;
    int ibeg = blockIdx.z * 512;
    short8 Qa = *(const short8*)(Qh + (size_t)(ibeg + il) * HD + g * 8);
    short8 Qb = *(const short8*)(Qh + (size_t)(ibeg + 16 + il) * HD + g * 8);
    for (int i0 = ibeg; i0 < ibeg + 512; i0 += 32) {
        short8 cQa = Qa, cQb = Qb;
        int in = (i0 + 32 < ibeg + 512) ? i0 + 32 : i0;   // prefetch next (dummy on last)
        Qa = *(const short8*)(Qh + (size_t)(in + il) * HD + g * 8);
        Qb = *(const short8*)(Qh + (size_t)(in + 16 + il) * HD + g * 8);
        f32x4 Saa = __builtin_amdgcn_mfma_f32_16x16x32_bf16(cQa, Kf0, z, 0, 0, 0);
        f32x4 Sab = __builtin_amdgcn_mfma_f32_16x16x32_bf16(cQa, Kf1, z, 0, 0, 0);
        f32x4 Sba = __builtin_amdgcn_mfma_f32_16x16x32_bf16(cQb, Kf0, z, 0, 0, 0);
        f32x4 Sbb = __builtin_amdgcn_mfma_f32_16x16x32_bf16(cQb, Kf1, z, 0, 0, 0);
        s0 += (__builtin_amdgcn_exp2f(Saa[0]) + __builtin_amdgcn_exp2f(Saa[1]))
            + (__builtin_amdgcn_exp2f(Saa[2]) + __builtin_amdgcn_exp2f(Saa[3]))
            + (__builtin_amdgcn_exp2f(Sba[0]) + __builtin_amdgcn_exp2f(Sba[1]))
            + (__builtin_amdgcn_exp2f(Sba[2]) + __builtin_amdgcn_exp2f(Sba[3]));
        s1 += (__builtin_amdgcn_exp2f(Sab[0]) + __builtin_amdgcn_exp2f(Sab[1]))
            + (__builtin_amdgcn_exp2f(Sab[2]) + __builtin_amdgcn_exp2f(Sab[3]))
            + (__builtin_amdgcn_exp2f(Sbb[0]) + __builtin_amdgcn_exp2f(Sbb[1]))
            + (__builtin_amdgcn_exp2f(Sbb[2]) + __builtin_amdgcn_exp2f(Sbb[3]));
    }
#pragma unroll
    for (int off = 16; off <= 32; off <<= 1) {
        s0 += __shfl_xor(s0, off);
        s1 += __shfl_xor(s1, off);
    }
    if (g == 0) {
        atomicAdd(&colS[(size_t)h * N + j0 + il], s0);
        atomicAdd(&colS[(size_t)h * N + j0 + 16 + il], s1);
    }
}

// ---- lc2 = log2(sigG / colS), 32768 elements ----
__global__ void k_lc2(const float* __restrict__ sigG, const float* __restrict__ colS,
                      float* __restrict__ lc2) {
    int t = blockIdx.x * blockDim.x + threadIdx.x;
    f32x4 a = ((const f32x4*)sigG)[t];
    f32x4 b = ((const f32x4*)colS)[t];
    f32x4 o;
#pragma unroll
    for (int r = 0; r < 4; ++r) o[r] = __builtin_amdgcn_logf(a[r] / b[r]);
    ((f32x4*)lc2)[t] = o;
}

// Assemble PV A-frag in registers from swapped-QK outputs.
// Inputs: Sa = scores for j-half0 (lane(il,g) holds j=4g+r, i=il),
//         Sb = j-half1. Output: lane(il,g) holds P[i=il][j=8g..8g+7] as short8.
static __device__ __forceinline__ short8 frag_dance(f32x4 Sa, f32x4 Sb) {
    unsigned A0 = packbf2(__builtin_amdgcn_exp2f(Sa[0]), __builtin_amdgcn_exp2f(Sa[1]));
    unsigned A1 = packbf2(__builtin_amdgcn_exp2f(Sa[2]), __builtin_amdgcn_exp2f(Sa[3]));
    unsigned B0 = packbf2(__builtin_amdgcn_exp2f(Sb[0]), __builtin_amdgcn_exp2f(Sb[1]));
    unsigned B1 = packbf2(__builtin_amdgcn_exp2f(Sb[2]), __builtin_amdgcn_exp2f(Sb[3]));
    uint2v r1 = __builtin_amdgcn_permlane32_swap(A0, B0, false, false);
    uint2v r2 = __builtin_amdgcn_permlane16_swap(r1[0], r1[1], false, false); // dw0, dw2
    uint2v r3 = __builtin_amdgcn_permlane32_swap(A1, B1, false, false);
    uint2v r4 = __builtin_amdgcn_permlane16_swap(r3[0], r3[1], false, false); // dw1, dw3
    uint4v pu;
    pu[0] = r2[0]; pu[1] = r4[0]; pu[2] = r2[1]; pu[3] = r4[1];
    return __builtin_bit_cast(short8, pu);
}

// ---- pass 2: Vpart[z][h][i][d] = sum_{j in chunk} 2^(S2+lc2[j]) * V[j,d] ----
// grid (16, NH, CH): x*4+w = i-tile of 64 rows (4 Q-frags), z = j-chunk of 512.
// 1-deep K/V software pipeline: iter k computes on regs loaded at iter k-1.
__global__ __launch_bounds__(256) void k_pass2(const unsigned short* __restrict__ Qp,
                                               const unsigned short* __restrict__ Kp,
                                               const unsigned short* __restrict__ VpT,
                                               const float* __restrict__ lc2,
                                               float* __restrict__ Vpart) {
    int w = threadIdx.x >> 6, l = threadIdx.x & 63;
    int il = l & 15, g = l >> 4;
    int h = blockIdx.y;
    int i0 = (blockIdx.x * 4 + w) * 64;
    int jbeg = blockIdx.z * JSPAN;
    const unsigned short* Qh = Qp + (size_t)h * N * HD;
    const unsigned short* Kh = Kp + ((size_t)h * N + jbeg) * HD;
    const unsigned short* Vh = VpT + (size_t)h * HD * N + jbeg;
    const float* lcg = lc2 + (size_t)h * N + jbeg;
    short8 Qf[4];
#pragma unroll
    for (int q = 0; q < 4; ++q)
        Qf[q] = *(const short8*)(Qh + (size_t)(i0 + q * 16 + il) * HD + g * 8);
    f32x4 acc[4][2];
#pragma unroll
    for (int q = 0; q < 4; ++q) {
        acc[q][0] = {0.f, 0.f, 0.f, 0.f};
        acc[q][1] = {0.f, 0.f, 0.f, 0.f};
    }
    // prologue: load jb = 0 operands
    short8 K0 = *(const short8*)(Kh + (size_t)il * HD + g * 8);
    short8 K1 = *(const short8*)(Kh + (size_t)(16 + il) * HD + g * 8);
    short8 V0 = *(const short8*)(Vh + (size_t)il * N + g * 8);
    short8 V1 = *(const short8*)(Vh + (size_t)(16 + il) * N + g * 8);
    for (int jb = 0; jb < JSPAN; jb += 32) {
        short8 cK0 = K0, cK1 = K1, cV0 = V0, cV1 = V1;
        int jn = (jb + 32 < JSPAN) ? jb + 32 : jb;   // prefetch next (dummy on last)
        K0 = *(const short8*)(Kh + (size_t)(jn + il) * HD + g * 8);
        K1 = *(const short8*)(Kh + (size_t)(jn + 16 + il) * HD + g * 8);
        V0 = *(const short8*)(Vh + (size_t)il * N + jn + g * 8);
        V1 = *(const short8*)(Vh + (size_t)(16 + il) * N + jn + g * 8);
        f32x4 lcvA = *(const f32x4*)(lcg + jb + g * 4);
        f32x4 lcvB = *(const f32x4*)(lcg + jb + 16 + g * 4);
#pragma unroll
        for (int q = 0; q < 4; ++q) {
            // swapped QK: lane(il,g) gets S[j=4g+r][i=il] (+lc2 via C-operand)
            f32x4 SA = __builtin_amdgcn_mfma_f32_16x16x32_bf16(cK0, Qf[q], lcvA, 0, 0, 0);
            f32x4 SB = __builtin_amdgcn_mfma_f32_16x16x32_bf16(cK1, Qf[q], lcvB, 0, 0, 0);
            short8 Pa = frag_dance(SA, SB);
            acc[q][0] = __builtin_amdgcn_mfma_f32_16x16x32_bf16(Pa, cV0, acc[q][0], 0, 0, 0);
            acc[q][1] = __builtin_amdgcn_mfma_f32_16x16x32_bf16(Pa, cV1, acc[q][1], 0, 0, 0);
        }
    }
    float* Vout = Vpart + (size_t)(blockIdx.z * NH + h) * N * HD;
#pragma unroll
    for (int q = 0; q < 4; ++q) {
#pragma unroll
        for (int r = 0; r < 4; ++r) {
            int ia = i0 + q * 16 + g * 4 + r;
            Vout[(size_t)ia * HD + il]      = acc[q][0][r];   // coalesced 64B/quarter-wave
            Vout[(size_t)ia * HD + 16 + il] = acc[q][1][r];
        }
    }
}

// ---- layernorm: sum CH partials (layout [ch][h][i][d]), normalize, scatter ----
__global__ __launch_bounds__(256) void k_ln(const float* __restrict__ Vpart,
                                            const float* __restrict__ gam,
                                            const float* __restrict__ bet,
                                            float* __restrict__ out) {
    int w = threadIdx.x >> 6, l = threadIdx.x & 63;
    int i = blockIdx.x * 4 + w;
    int h = l >> 3, d0 = (l & 7) << 2;   // lane owns channels c = (d0+r)*8 + h
    f32x4 x = {0.f, 0.f, 0.f, 0.f};
#pragma unroll
    for (int c = 0; c < CH; ++c) {
        f32x4 v = *(const f32x4*)(Vpart + ((size_t)(c * NH + h) * N + i) * HD + d0);
        x[0] += v[0]; x[1] += v[1]; x[2] += v[2]; x[3] += v[3];
    }
    float s1 = x[0] + x[1] + x[2] + x[3];
    float s2 = x[0] * x[0] + x[1] * x[1] + x[2] * x[2] + x[3] * x[3];
#pragma unroll
    for (int off = 1; off < 64; off <<= 1) {
        s1 += __shfl_xor(s1, off);
        s2 += __shfl_xor(s2, off);
    }
    float mu = s1 * (1.f / 256.f);
    float var = s2 * (1.f / 256.f) - mu * mu;
    float rs = rsqrtf(var + 1e-3f);
#pragma unroll
    for (int r = 0; r < 4; ++r) {
        int c = (d0 + r) * 8 + h;
        out[(size_t)i * HID + c] = (x[r] - mu) * rs * gam[c] + bet[c];
    }
}

extern "C" void kernel_launch(void* const* d_in, const int* in_sizes, int n_in,
                              void* d_out, int out_size, void* d_ws, size_t ws_size,
                              hipStream_t stream) {
    const float* feat = (const float*)d_in[0];
    const float* Wq   = (const float*)d_in[1];
    const float* bq   = (const float*)d_in[2];
    const float* Wkv  = (const float*)d_in[3];
    const float* bkv  = (const float*)d_in[4];
    const float* Weg  = (const float*)d_in[5];
    const float* beg  = (const float*)d_in[6];
    const float* ln_g = (const float*)d_in[7];
    const float* ln_b = (const float*)d_in[8];
    float* out = (float*)d_out;

    char* ws = (char*)d_ws;
    unsigned short* Qp    = (unsigned short*)(ws + 0);                     // 2 MB
    unsigned short* Kp    = (unsigned short*)(ws + (2u << 20));            // 2 MB
    unsigned short* VpT   = (unsigned short*)(ws + (4u << 20));            // 2 MB
    unsigned short* featb = (unsigned short*)(ws + (6u << 20));            // 2 MB
    unsigned short* WbT   = (unsigned short*)(ws + (8u << 20));            // 0.4 MB
    float* bC   = (float*)(ws + (8u << 20) + (512u << 10));                // 3 KB
    float* sigG = (float*)(ws + (8u << 20) + (528u << 10));                // 128 KB
    float* colS = (float*)(ws + (8u << 20) + (656u << 10));                // 128 KB
    float* lc2  = (float*)(ws + (8u << 20) + (784u << 10));                // 128 KB
    float* Vpart = (float*)(ws + (9u << 20));                              // CH*4 MB

    k_prep<<<dim3(1024 + NC), 256, 0, stream>>>(feat, Wq, Wkv, Weg, bq, bkv, beg,
                                                featb, WbT, bC, colS);
    k_proj<<<dim3(49, 64), 256, 0, stream>>>(featb, WbT, bC, Qp, Kp, VpT, sigG);
    k_pass1<<<dim3(32, NH, 8), 256, 0, stream>>>(Qp, Kp, colS);
    k_lc2<<<dim3(32), 256, 0, stream>>>(sigG, colS, lc2);
    k_pass2<<<dim3(16, NH, CH), 256, 0, stream>>>(Qp, Kp, VpT, lc2, Vpart);
    k_ln<<<dim3(1024), 256, 0, stream>>>(Vpart, ln_g, ln_b, out);
}